// Round 1
// baseline (47.986 us; speedup 1.0000x reference)
//
#include <hip/hip_runtime.h>

// ROIAlign (aligned=True, TF crop_and_resize semantics), NHWC fp32.
// inputs: [2,100,100,256] f32; boxes: [1024,4] f32 (x0,y0,x1,y1);
// box_inds: [1024] i32; out: [1024,7,7,256] f32.

constexpr int   H_IN  = 100;
constexpr int   W_IN  = 100;
constexpr int   C_IN  = 256;
constexpr int   OUT_H = 7;
constexpr int   OUT_W = 7;
constexpr int   SR    = 2;           // sampling ratio
constexpr int   NPIX  = OUT_H * OUT_W;   // 49
constexpr float SCALE = 0.125f;

// One 64-lane wave group per output pixel; each lane handles 4 channels (float4).
// Block = 256 threads = 4 pixels.
__global__ __launch_bounds__(256) void roi_align_kernel(
    const float* __restrict__ inputs,
    const float* __restrict__ boxes,
    const int*   __restrict__ box_inds,
    float*       __restrict__ out)
{
    const int tid  = threadIdx.x;
    const int lane = tid & 63;        // channel group
    const int sub  = tid >> 6;        // which pixel within block
    const int p    = blockIdx.x * 4 + sub;       // global pixel id [0, 50176)

    const int b   = p / NPIX;
    const int rem = p - b * NPIX;
    const int oy  = rem / OUT_W;
    const int ox  = rem - oy * OUT_W;

    // Box params (wave-uniform)
    const float x0 = boxes[b * 4 + 0] * SCALE;
    const float y0 = boxes[b * 4 + 1] * SCALE;
    const float x1 = boxes[b * 4 + 2] * SCALE;
    const float y1 = boxes[b * 4 + 3] * SCALE;
    const float sw = (x1 - x0) * (1.0f / (OUT_W * SR));
    const float sh = (y1 - y0) * (1.0f / (OUT_H * SR));
    const int   n  = box_inds[b];

    const float* base = inputs + (size_t)n * (H_IN * W_IN * C_IN);
    const int c4 = lane * 4;

    float ax = 0.f, ay = 0.f, az = 0.f, aw = 0.f;

#pragma unroll
    for (int sy = 0; sy < SR; ++sy) {
        const float ysv = y0 + sh * ((float)(oy * SR + sy) + 0.5f) - 0.5f;
        if (ysv < 0.0f || ysv > (float)(H_IN - 1)) continue;
        const float yl = floorf(ysv);
        const float ty = ysv - yl;
        const int yli = (int)yl;
        const int yhi = min(yli + 1, H_IN - 1);
#pragma unroll
        for (int sx = 0; sx < SR; ++sx) {
            const float xsv = x0 + sw * ((float)(ox * SR + sx) + 0.5f) - 0.5f;
            if (xsv < 0.0f || xsv > (float)(W_IN - 1)) continue;
            const float xl = floorf(xsv);
            const float tx = xsv - xl;
            const int xli = (int)xl;
            const int xhi = min(xli + 1, W_IN - 1);

            const float w00 = (1.0f - ty) * (1.0f - tx);
            const float w01 = (1.0f - ty) * tx;
            const float w10 = ty * (1.0f - tx);
            const float w11 = ty * tx;

            const float4 v00 = *(const float4*)(base + ((size_t)(yli * W_IN + xli) * C_IN) + c4);
            const float4 v01 = *(const float4*)(base + ((size_t)(yli * W_IN + xhi) * C_IN) + c4);
            const float4 v10 = *(const float4*)(base + ((size_t)(yhi * W_IN + xli) * C_IN) + c4);
            const float4 v11 = *(const float4*)(base + ((size_t)(yhi * W_IN + xhi) * C_IN) + c4);

            ax += v00.x * w00 + v01.x * w01 + v10.x * w10 + v11.x * w11;
            ay += v00.y * w00 + v01.y * w01 + v10.y * w10 + v11.y * w11;
            az += v00.z * w00 + v01.z * w01 + v10.z * w10 + v11.z * w11;
            aw += v00.w * w00 + v01.w * w01 + v10.w * w10 + v11.w * w11;
        }
    }

    float4 res;
    res.x = ax * 0.25f;
    res.y = ay * 0.25f;
    res.z = az * 0.25f;
    res.w = aw * 0.25f;
    *(float4*)(out + (size_t)p * C_IN + c4) = res;
}

extern "C" void kernel_launch(void* const* d_in, const int* in_sizes, int n_in,
                              void* d_out, int out_size, void* d_ws, size_t ws_size,
                              hipStream_t stream) {
    const float* inputs   = (const float*)d_in[0];
    const float* boxes    = (const float*)d_in[1];
    const int*   box_inds = (const int*)d_in[2];
    float*       out      = (float*)d_out;

    const int npix_total = 1024 * NPIX;           // 50176
    const int blocks     = npix_total / 4;        // 12544
    roi_align_kernel<<<blocks, 256, 0, stream>>>(inputs, boxes, box_inds, out);
}

// Round 3
// 38.347 us; speedup vs baseline: 1.2514x; 1.2514x over previous
//
#include <hip/hip_runtime.h>

// ROIAlign (aligned=True, TF crop_and_resize semantics), NHWC fp32.
// inputs: [2,100,100,256] f32; boxes: [1024,4] f32 (x0,y0,x1,y1);
// box_inds: [1024] i32; out: [1024,7,7,256] f32.

constexpr int   H_IN  = 100;
constexpr int   W_IN  = 100;
constexpr int   C_IN  = 256;
constexpr int   OUT_H = 7;
constexpr int   OUT_W = 7;
constexpr int   SR    = 2;               // sampling ratio
constexpr int   NPIX  = OUT_H * OUT_W;   // 49
constexpr float SCALE = 0.125f;

typedef float f32x4 __attribute__((ext_vector_type(4)));   // native vec4 (works with nontemporal builtins)

// One 64-lane wave per output pixel; each lane handles 4 channels (float4).
// Block = 256 threads = 4 pixels. All 16 corner loads issued branchlessly
// (validity folded into weights, addresses clamped in-range) for max MLP.
__global__ __launch_bounds__(256) void roi_align_kernel(
    const float* __restrict__ inputs,
    const float* __restrict__ boxes,
    const int*   __restrict__ box_inds,
    float*       __restrict__ out)
{
    const int tid  = threadIdx.x;
    const int lane = tid & 63;        // channel group
    const int sub  = tid >> 6;        // pixel within block

    // XCD-chunked swizzle: consecutive logical blocks (same box) -> same XCD.
    // grid = 12544, divisible by 8.
    const int nchunk = gridDim.x >> 3;
    const int lbid   = (blockIdx.x & 7) * nchunk + (blockIdx.x >> 3);
    const int p      = lbid * 4 + sub;           // global pixel id [0, 50176)

    const int b   = p / NPIX;
    const int rem = p - b * NPIX;
    const int oy  = rem / OUT_W;
    const int ox  = rem - oy * OUT_W;

    // Box params (wave-uniform)
    const float x0 = boxes[b * 4 + 0] * SCALE;
    const float y0 = boxes[b * 4 + 1] * SCALE;
    const float x1 = boxes[b * 4 + 2] * SCALE;
    const float y1 = boxes[b * 4 + 3] * SCALE;
    const float sw = (x1 - x0) * (1.0f / (OUT_W * SR));
    const float sh = (y1 - y0) * (1.0f / (OUT_H * SR));
    const int   n  = box_inds[b];

    const float* base = inputs + (size_t)n * (H_IN * W_IN * C_IN);
    const int c4 = lane * 4;

    // y samples: row offsets + validity-folded weights
    int   rowoff[2][2];
    float wy[2][2];
#pragma unroll
    for (int sy = 0; sy < 2; ++sy) {
        const float ysv   = y0 + sh * ((float)(oy * SR + sy) + 0.5f) - 0.5f;
        const float valid = (ysv >= 0.0f && ysv <= (float)(H_IN - 1)) ? 1.0f : 0.0f;
        const float yl    = floorf(ysv);
        const float ty    = ysv - yl;
        const int   yli   = min(max((int)yl, 0), H_IN - 1);
        const int   yhi   = min(yli + 1, H_IN - 1);
        rowoff[sy][0] = yli * W_IN;
        rowoff[sy][1] = yhi * W_IN;
        wy[sy][0] = valid * (1.0f - ty);
        wy[sy][1] = valid * ty;
    }

    // x samples: col offsets + validity-folded weights
    int   coloff[2][2];
    float wx[2][2];
#pragma unroll
    for (int sx = 0; sx < 2; ++sx) {
        const float xsv   = x0 + sw * ((float)(ox * SR + sx) + 0.5f) - 0.5f;
        const float valid = (xsv >= 0.0f && xsv <= (float)(W_IN - 1)) ? 1.0f : 0.0f;
        const float xl    = floorf(xsv);
        const float tx    = xsv - xl;
        const int   xli   = min(max((int)xl, 0), W_IN - 1);
        const int   xhi   = min(xli + 1, W_IN - 1);
        coloff[sx][0] = xli;
        coloff[sx][1] = xhi;
        wx[sx][0] = valid * (1.0f - tx);
        wx[sx][1] = valid * tx;
    }

    // Issue all 16 corner loads back-to-back (no branches -> deep MLP).
    f32x4 v[16];
#pragma unroll
    for (int sy = 0; sy < 2; ++sy)
#pragma unroll
        for (int yy = 0; yy < 2; ++yy)
#pragma unroll
            for (int sx = 0; sx < 2; ++sx)
#pragma unroll
                for (int xx = 0; xx < 2; ++xx)
                    v[((sy * 2 + yy) * 2 + sx) * 2 + xx] =
                        *(const f32x4*)(base + (size_t)((rowoff[sy][yy] + coloff[sx][xx]) * C_IN + c4));

    f32x4 acc = {0.f, 0.f, 0.f, 0.f};
#pragma unroll
    for (int sy = 0; sy < 2; ++sy)
#pragma unroll
        for (int yy = 0; yy < 2; ++yy)
#pragma unroll
            for (int sx = 0; sx < 2; ++sx)
#pragma unroll
                for (int xx = 0; xx < 2; ++xx) {
                    const float w = wy[sy][yy] * wx[sx][xx];
                    acc += v[((sy * 2 + yy) * 2 + sx) * 2 + xx] * w;
                }

    acc *= 0.25f;

    // Streaming output: nontemporal store keeps L2 free for the gathers.
    float* op = out + (size_t)p * C_IN + c4;
    __builtin_nontemporal_store(acc, (f32x4*)op);
}

extern "C" void kernel_launch(void* const* d_in, const int* in_sizes, int n_in,
                              void* d_out, int out_size, void* d_ws, size_t ws_size,
                              hipStream_t stream) {
    const float* inputs   = (const float*)d_in[0];
    const float* boxes    = (const float*)d_in[1];
    const int*   box_inds = (const int*)d_in[2];
    float*       out      = (float*)d_out;

    const int npix_total = 1024 * NPIX;           // 50176
    const int blocks     = npix_total / 4;        // 12544
    roi_align_kernel<<<blocks, 256, 0, stream>>>(inputs, boxes, box_inds, out);
}

// Round 4
// 34.945 us; speedup vs baseline: 1.3732x; 1.0973x over previous
//
#include <hip/hip_runtime.h>

// ROIAlign (aligned=True, TF crop_and_resize semantics), NHWC fp32.
// inputs: [2,100,100,256] f32; boxes: [1024,4] f32 (x0,y0,x1,y1);
// box_inds: [1024] i32; out: [1024,7,7,256] f32.
//
// Key identity: summing the 2x2 samples' bilinear weights is separable:
//   total_weight(R,C) = (sum_sy wy_R(sy)) * (sum_sx wx_C(sx))
// so duplicate rows/cols across samples can be merged exactly, reducing the
// 16 corner loads to nr*nc unique loads, nr,nc in {2,3,4} (avg ~8.6).

constexpr int   H_IN  = 100;
constexpr int   W_IN  = 100;
constexpr int   C_IN  = 256;
constexpr int   OUT_H = 7;
constexpr int   OUT_W = 7;
constexpr int   SR    = 2;               // sampling ratio
constexpr int   NPIX  = OUT_H * OUT_W;   // 49
constexpr float SCALE = 0.125f;

typedef float f32x4 __attribute__((ext_vector_type(4)));

template<int NR, int NC>
__device__ __forceinline__ f32x4 gather(const float* __restrict__ base,
                                        const int* ro, const int* co,
                                        const float* wr, const float* wc,
                                        int c4)
{
    f32x4 v[NR * NC];
#pragma unroll
    for (int i = 0; i < NR; ++i)
#pragma unroll
        for (int j = 0; j < NC; ++j)
            v[i * NC + j] = *(const f32x4*)(base + (size_t)((ro[i] + co[j]) * C_IN + c4));

    f32x4 acc = {0.f, 0.f, 0.f, 0.f};
#pragma unroll
    for (int i = 0; i < NR; ++i)
#pragma unroll
        for (int j = 0; j < NC; ++j)
            acc += v[i * NC + j] * (wr[i] * wc[j]);
    return acc;
}

// Per-dimension: compute merged (index, folded-weight) list for the 2 samples'
// bilinear footprints. s0,s1 = sample coords; LIM = dim size.
// Returns count (2..4); idx[] unclamped-merged then clamped; w[] validity-folded.
__device__ __forceinline__ int merge_dim(float s0, float s1, int LIM,
                                         int* idx, float* w)
{
    const float f0 = floorf(s0);
    const float f1 = floorf(s1);
    const float t0 = s0 - f0;
    const float t1 = s1 - f1;
    const float va = (s0 >= 0.0f && s0 <= (float)(LIM - 1)) ? 1.0f : 0.0f;
    const float vb = (s1 >= 0.0f && s1 <= (float)(LIM - 1)) ? 1.0f : 0.0f;
    const int i0 = (int)f0;
    const int i1 = (int)f1;

    int n;
    if (i1 == i0) {                 // both samples in the same cell
        n = 2;
        idx[0] = i0;     w[0] = va * (1.0f - t0) + vb * (1.0f - t1);
        idx[1] = i0 + 1; w[1] = va * t0 + vb * t1;
    } else if (i1 == i0 + 1) {      // adjacent cells, shared middle line
        n = 3;
        idx[0] = i0;     w[0] = va * (1.0f - t0);
        idx[1] = i0 + 1; w[1] = va * t0 + vb * (1.0f - t1);
        idx[2] = i0 + 2; w[2] = vb * t1;
    } else {                        // disjoint cells
        n = 4;
        idx[0] = i0;     w[0] = va * (1.0f - t0);
        idx[1] = i0 + 1; w[1] = va * t0;
        idx[2] = i1;     w[2] = vb * (1.0f - t1);
        idx[3] = i1 + 1; w[3] = vb * t1;
    }
#pragma unroll
    for (int k = 0; k < 4; ++k)     // clamp for addressing (weights already 0 when invalid)
        idx[k] = min(max(idx[k], 0), LIM - 1);
    return n;
}

// One 64-lane wave per output pixel; each lane handles 4 channels (f32x4).
// Block = 256 threads = 4 pixels.
__global__ __launch_bounds__(256) void roi_align_kernel(
    const float* __restrict__ inputs,
    const float* __restrict__ boxes,
    const int*   __restrict__ box_inds,
    float*       __restrict__ out)
{
    const int tid  = threadIdx.x;
    const int lane = tid & 63;        // channel group
    const int sub  = tid >> 6;        // pixel within block

    // XCD-chunked swizzle: consecutive logical blocks (same box) -> same XCD.
    // grid = 12544, divisible by 8.
    const int nchunk = gridDim.x >> 3;
    const int lbid   = (blockIdx.x & 7) * nchunk + (blockIdx.x >> 3);
    const int p      = lbid * 4 + sub;           // global pixel id [0, 50176)

    const int b   = p / NPIX;
    const int rem = p - b * NPIX;
    const int oy  = rem / OUT_W;
    const int ox  = rem - oy * OUT_W;

    // Box params (wave-uniform)
    const float x0 = boxes[b * 4 + 0] * SCALE;
    const float y0 = boxes[b * 4 + 1] * SCALE;
    const float x1 = boxes[b * 4 + 2] * SCALE;
    const float y1 = boxes[b * 4 + 3] * SCALE;
    const float sw = (x1 - x0) * (1.0f / (OUT_W * SR));
    const float sh = (y1 - y0) * (1.0f / (OUT_H * SR));
    const int   n  = box_inds[b];

    const float* base = inputs + (size_t)n * (H_IN * W_IN * C_IN);
    const int c4 = lane * 4;

    // y dimension: 2 sample rows -> merged row list
    const float ys0 = y0 + sh * ((float)(oy * SR) + 0.5f) - 0.5f;
    const float ys1 = ys0 + sh;
    int   ridx[4]; float wr[4];
    const int nr = merge_dim(ys0, ys1, H_IN, ridx, wr);
#pragma unroll
    for (int k = 0; k < 4; ++k) ridx[k] *= W_IN;   // row offsets

    // x dimension
    const float xs0 = x0 + sw * ((float)(ox * SR) + 0.5f) - 0.5f;
    const float xs1 = xs0 + sw;
    int   cidx[4]; float wc[4];
    const int nc = merge_dim(xs0, xs1, W_IN, cidx, wc);

    // Wave-uniform dispatch (values identical across lanes; hoist to SGPR).
    const int sel = __builtin_amdgcn_readfirstlane((nr - 2) * 3 + (nc - 2));

    f32x4 acc;
    switch (sel) {
        case 0: acc = gather<2, 2>(base, ridx, cidx, wr, wc, c4); break;
        case 1: acc = gather<2, 3>(base, ridx, cidx, wr, wc, c4); break;
        case 2: acc = gather<2, 4>(base, ridx, cidx, wr, wc, c4); break;
        case 3: acc = gather<3, 2>(base, ridx, cidx, wr, wc, c4); break;
        case 4: acc = gather<3, 3>(base, ridx, cidx, wr, wc, c4); break;
        case 5: acc = gather<3, 4>(base, ridx, cidx, wr, wc, c4); break;
        case 6: acc = gather<4, 2>(base, ridx, cidx, wr, wc, c4); break;
        case 7: acc = gather<4, 3>(base, ridx, cidx, wr, wc, c4); break;
        default: acc = gather<4, 4>(base, ridx, cidx, wr, wc, c4); break;
    }

    acc *= 0.25f;

    // Streaming output: nontemporal store keeps L2 free for the gathers.
    float* op = out + (size_t)p * C_IN + c4;
    __builtin_nontemporal_store(acc, (f32x4*)op);
}

extern "C" void kernel_launch(void* const* d_in, const int* in_sizes, int n_in,
                              void* d_out, int out_size, void* d_ws, size_t ws_size,
                              hipStream_t stream) {
    const float* inputs   = (const float*)d_in[0];
    const float* boxes    = (const float*)d_in[1];
    const int*   box_inds = (const int*)d_in[2];
    float*       out      = (float*)d_out;

    const int npix_total = 1024 * NPIX;           // 50176
    const int blocks     = npix_total / 4;        // 12544
    roi_align_kernel<<<blocks, 256, 0, stream>>>(inputs, boxes, box_inds, out);
}

// Round 5
// 31.785 us; speedup vs baseline: 1.5097x; 1.0994x over previous
//
#include <hip/hip_runtime.h>

// ROIAlign (aligned=True, TF crop_and_resize semantics), NHWC fp32.
// inputs: [2,100,100,256] f32; boxes: [1024,4] f32 (x0,y0,x1,y1);
// box_inds: [1024] i32; out: [1024,7,7,256] f32.
//
// Round-5 structure:
//  - kernel A: ballot-sort the 1024 boxes by spatial bin
//    (image_index*4 + y-band) so each XCD chunk's 128 boxes share a ~3.3 MB
//    slice of the feature map that FITS the 4 MB per-XCD L2.
//  - kernel B: separable-merged bilinear gather (nr*nc unique corners,
//    nr,nc in {2,3,4}), one wave per output pixel, f32x4 per lane.

constexpr int   H_IN  = 100;
constexpr int   W_IN  = 100;
constexpr int   C_IN  = 256;
constexpr int   OUT_H = 7;
constexpr int   OUT_W = 7;
constexpr int   SR    = 2;               // sampling ratio
constexpr int   NPIX  = OUT_H * OUT_W;   // 49
constexpr int   NBOX  = 1024;
constexpr float SCALE = 0.125f;

typedef float f32x4 __attribute__((ext_vector_type(4)));

// ---------------- kernel A: spatial box sort (1 block, 1024 threads) -------
__global__ __launch_bounds__(1024) void sort_boxes_kernel(
    const float* __restrict__ boxes,
    const int*   __restrict__ box_inds,
    int*         __restrict__ perm)       // d_ws, NBOX ints
{
    const int tid  = threadIdx.x;
    const int wave = tid >> 6;
    const int lane = tid & 63;

    const float y0 = boxes[tid * 4 + 1] * SCALE;
    const float y1 = boxes[tid * 4 + 3] * SCALE;
    const float cy = 0.5f * (y0 + y1);
    int band = (int)(cy * (1.0f / 25.0f));
    band = min(max(band, 0), 3);
    const int bin = box_inds[tid] * 4 + band;   // 0..7

    __shared__ int whist[16][8];   // per-wave bin counts
    __shared__ int wbase[16][8];   // exclusive scan, bin-major

    int wrank = 0;
    const unsigned long long ltmask = (lane == 63) ? ~0ull >> 1
                                                   : (1ull << lane) - 1;
#pragma unroll
    for (int k = 0; k < 8; ++k) {
        const unsigned long long bal = __ballot(bin == k);
        if (bin == k) wrank = __popcll(bal & ltmask);
        if (lane == 0) whist[wave][k] = __popcll(bal);
    }
    __syncthreads();

    if (tid == 0) {
        int acc = 0;
        for (int k = 0; k < 8; ++k)
            for (int w = 0; w < 16; ++w) {
                wbase[w][k] = acc;
                acc += whist[w][k];
            }
    }
    __syncthreads();

    perm[wbase[wave][bin] + wrank] = tid;
}

// ---------------- kernel B: main gather -----------------------------------
template<int NR, int NC>
__device__ __forceinline__ f32x4 gather(const float* __restrict__ base,
                                        const int* ro, const int* co,
                                        const float* wr, const float* wc,
                                        int c4)
{
    f32x4 v[NR * NC];
#pragma unroll
    for (int i = 0; i < NR; ++i)
#pragma unroll
        for (int j = 0; j < NC; ++j)
            v[i * NC + j] = *(const f32x4*)(base + (size_t)((ro[i] + co[j]) * C_IN + c4));

    f32x4 acc = {0.f, 0.f, 0.f, 0.f};
#pragma unroll
    for (int i = 0; i < NR; ++i)
#pragma unroll
        for (int j = 0; j < NC; ++j)
            acc += v[i * NC + j] * (wr[i] * wc[j]);
    return acc;
}

__device__ __forceinline__ int merge_dim(float s0, float s1, int LIM,
                                         int* idx, float* w)
{
    const float f0 = floorf(s0);
    const float f1 = floorf(s1);
    const float t0 = s0 - f0;
    const float t1 = s1 - f1;
    const float va = (s0 >= 0.0f && s0 <= (float)(LIM - 1)) ? 1.0f : 0.0f;
    const float vb = (s1 >= 0.0f && s1 <= (float)(LIM - 1)) ? 1.0f : 0.0f;
    const int i0 = (int)f0;
    const int i1 = (int)f1;

    int n;
    if (i1 == i0) {                 // both samples in the same cell
        n = 2;
        idx[0] = i0;     w[0] = va * (1.0f - t0) + vb * (1.0f - t1);
        idx[1] = i0 + 1; w[1] = va * t0 + vb * t1;
    } else if (i1 == i0 + 1) {      // adjacent cells, shared middle line
        n = 3;
        idx[0] = i0;     w[0] = va * (1.0f - t0);
        idx[1] = i0 + 1; w[1] = va * t0 + vb * (1.0f - t1);
        idx[2] = i0 + 2; w[2] = vb * t1;
    } else {                        // disjoint cells
        n = 4;
        idx[0] = i0;     w[0] = va * (1.0f - t0);
        idx[1] = i0 + 1; w[1] = va * t0;
        idx[2] = i1;     w[2] = vb * (1.0f - t1);
        idx[3] = i1 + 1; w[3] = vb * t1;
    }
#pragma unroll
    for (int k = 0; k < 4; ++k)     // clamp for addressing (weights already 0 when invalid)
        idx[k] = min(max(idx[k], 0), LIM - 1);
    return n;
}

__global__ __launch_bounds__(256) void roi_align_kernel(
    const float* __restrict__ inputs,
    const float* __restrict__ boxes,
    const int*   __restrict__ box_inds,
    const int*   __restrict__ perm,
    float*       __restrict__ out)
{
    const int tid  = threadIdx.x;
    const int lane = tid & 63;        // channel group
    const int sub  = tid >> 6;        // pixel within block

    // XCD-chunked swizzle: consecutive logical blocks -> same XCD.
    // grid = 12544 (divisible by 8); each chunk = 1568 blocks = 128 sorted boxes.
    const int nchunk = gridDim.x >> 3;
    const int lbid   = (blockIdx.x & 7) * nchunk + (blockIdx.x >> 3);
    const int p      = lbid * 4 + sub;           // sorted pixel id [0, 50176)

    const int bs  = p / NPIX;                    // sorted box slot
    const int b   = perm[bs];                    // real box id (hot 4 KB table)
    const int rem = p - bs * NPIX;
    const int oy  = rem / OUT_W;
    const int ox  = rem - oy * OUT_W;

    // Box params (wave-uniform)
    const float x0 = boxes[b * 4 + 0] * SCALE;
    const float y0 = boxes[b * 4 + 1] * SCALE;
    const float x1 = boxes[b * 4 + 2] * SCALE;
    const float y1 = boxes[b * 4 + 3] * SCALE;
    const float sw = (x1 - x0) * (1.0f / (OUT_W * SR));
    const float sh = (y1 - y0) * (1.0f / (OUT_H * SR));
    const int   n  = box_inds[b];

    const float* base = inputs + (size_t)n * (H_IN * W_IN * C_IN);
    const int c4 = lane * 4;

    // y dimension: 2 sample rows -> merged row list
    const float ys0 = y0 + sh * ((float)(oy * SR) + 0.5f) - 0.5f;
    const float ys1 = ys0 + sh;
    int   ridx[4]; float wr[4];
    const int nr = merge_dim(ys0, ys1, H_IN, ridx, wr);
#pragma unroll
    for (int k = 0; k < 4; ++k) ridx[k] *= W_IN;   // row offsets

    // x dimension
    const float xs0 = x0 + sw * ((float)(ox * SR) + 0.5f) - 0.5f;
    const float xs1 = xs0 + sw;
    int   cidx[4]; float wc[4];
    const int nc = merge_dim(xs0, xs1, W_IN, cidx, wc);

    // Wave-uniform dispatch (values identical across lanes; hoist to SGPR).
    const int sel = __builtin_amdgcn_readfirstlane((nr - 2) * 3 + (nc - 2));

    f32x4 acc;
    switch (sel) {
        case 0: acc = gather<2, 2>(base, ridx, cidx, wr, wc, c4); break;
        case 1: acc = gather<2, 3>(base, ridx, cidx, wr, wc, c4); break;
        case 2: acc = gather<2, 4>(base, ridx, cidx, wr, wc, c4); break;
        case 3: acc = gather<3, 2>(base, ridx, cidx, wr, wc, c4); break;
        case 4: acc = gather<3, 3>(base, ridx, cidx, wr, wc, c4); break;
        case 5: acc = gather<3, 4>(base, ridx, cidx, wr, wc, c4); break;
        case 6: acc = gather<4, 2>(base, ridx, cidx, wr, wc, c4); break;
        case 7: acc = gather<4, 3>(base, ridx, cidx, wr, wc, c4); break;
        default: acc = gather<4, 4>(base, ridx, cidx, wr, wc, c4); break;
    }

    acc *= 0.25f;

    // Streaming output: nontemporal store keeps L2 free for the gathers.
    float* op = out + (size_t)b * (NPIX * C_IN) + (size_t)rem * C_IN + c4;
    __builtin_nontemporal_store(acc, (f32x4*)op);
}

extern "C" void kernel_launch(void* const* d_in, const int* in_sizes, int n_in,
                              void* d_out, int out_size, void* d_ws, size_t ws_size,
                              hipStream_t stream) {
    const float* inputs   = (const float*)d_in[0];
    const float* boxes    = (const float*)d_in[1];
    const int*   box_inds = (const int*)d_in[2];
    float*       out      = (float*)d_out;
    int*         perm     = (int*)d_ws;           // NBOX ints

    sort_boxes_kernel<<<1, NBOX, 0, stream>>>(boxes, box_inds, perm);

    const int npix_total = NBOX * NPIX;           // 50176
    const int blocks     = npix_total / 4;        // 12544
    roi_align_kernel<<<blocks, 256, 0, stream>>>(inputs, boxes, box_inds, perm, out);
}